// Round 12
// baseline (149.771 us; speedup 1.0000x reference)
//
#include <hip/hip_runtime.h>
#include <hip/hip_bf16.h>

#define H_    32
#define HKV_  8
#define D_    128
#define HID_  4096
#define NQKV  6144            // 4096 + 1024 + 1024
#define SPLIT 128             // split-K for the GEMVs (rows per chunk = 32)
#define CHUNK 64              // tokens per attention block (all 8 kv-heads)
#define TB    4               // tokens per LDS tile (tile = TB*8 heads*512B, contiguous)
#define NT    (CHUNK / TB)    // 16 tiles per block
#define S_    32768
#define NCHUNK (S_ / CHUNK)   // 512
#define SCALE_ 0.08838834764831843f  // 1/sqrt(128)
#define BASE_  8.0f           // fixed softmax base: wgt = exp(s - 8), exact (cancels)

// async global->LDS copies (dest = wave-uniform base + lane*size)
#define GLOAD_LDS16(g, l) __builtin_amdgcn_global_load_lds( \
    (const __attribute__((address_space(1))) void*)(g),     \
    (__attribute__((address_space(3))) void*)(l), 16, 0, 0)
#define GLOAD_LDS4(g, l) __builtin_amdgcn_global_load_lds(  \
    (const __attribute__((address_space(1))) void*)(g),     \
    (__attribute__((address_space(3))) void*)(l), 4, 0, 0)

// workspace layout (float offsets).  PV_C overlays the QKV_PART scratch
// (QKV_PART is dead after k_qkv_reduce; k_attn rewrites every PV_C element).
#define WS_PV_C     0                       // [NCHUNK][HKV][4][D]    2097152
#define WS_QKV_PART 0                       // [SPLIT][NQKV]          786432 (dead after k2)
#define WS_QKV      2097152                 // [NQKV]                 6144
#define WS_L_C      2103296                 // [NCHUNK][HKV][4]       16384
#define WS_ATTN     2119680                 // [H*D]                  4096
#define WS_OPART    2123776                 // [SPLIT][HID]           524288
// total 2648064 floats = 10.6 MB

// ---------------- kernel 1: QKV GEMV split-K partials ----------------
__global__ __launch_bounds__(256) void k_qkv_part(
    const float* __restrict__ hid, const float* __restrict__ Wq,
    const float* __restrict__ Wk, const float* __restrict__ Wv,
    float* __restrict__ part)
{
    const int j0 = blockIdx.x * 1024 + threadIdx.x * 4;   // 6 col-blocks of 1024
    const int i0 = blockIdx.y * (HID_ / SPLIT);           // 32-row chunk
    __shared__ float hs[HID_ / SPLIT];
    if (threadIdx.x < HID_ / SPLIT) hs[threadIdx.x] = hid[i0 + threadIdx.x];
    __syncthreads();

    const float* W; int ldw; int col;
    if (j0 < 4096)       { W = Wq; ldw = 4096; col = j0; }
    else if (j0 < 5120)  { W = Wk; ldw = 1024; col = j0 - 4096; }
    else                 { W = Wv; ldw = 1024; col = j0 - 5120; }

    float4 acc = {0.f, 0.f, 0.f, 0.f};
    const float* p = W + (size_t)i0 * ldw + col;
    #pragma unroll 8
    for (int i = 0; i < HID_ / SPLIT; ++i) {
        const float4 wv = *(const float4*)(p + (size_t)i * ldw);
        const float h = hs[i];
        acc.x += h * wv.x; acc.y += h * wv.y; acc.z += h * wv.z; acc.w += h * wv.w;
    }
    *(float4*)&part[(size_t)blockIdx.y * NQKV + j0] = acc;
}

// ---------------- kernel 2: reduce partials + RoPE ----------------
__global__ __launch_bounds__(256) void k_qkv_reduce(
    const float* __restrict__ part, const float* __restrict__ cosv,
    const float* __restrict__ sinv, float* __restrict__ qkv)
{
    const int j = blockIdx.x * 256 + threadIdx.x;  // 24 blocks
    float s = 0.f;
    #pragma unroll 8
    for (int k = 0; k < SPLIT; ++k) s += part[(size_t)k * NQKV + j];
    __shared__ float buf[256];
    buf[threadIdx.x] = s;
    __syncthreads();
    float out = s;
    if (j < 5120) {  // q and k get RoPE; v passes through
        const int d = j & 127;
        const float rot = (d < 64) ? -buf[threadIdx.x + 64] : buf[threadIdx.x - 64];
        out = s * cosv[d] + rot * sinv[d];
    }
    qkv[j] = out;
}

// ---------------- kernel 3: fused flash-decode attention ----------------
// block = 512 thr = 8 waves; wave w = kv-head w (computes its 4 q-heads).
// A block covers a 64-token chunk across ALL 8 kv-heads, so the staged
// K/V tile (TB=4 tokens x 8 heads x 512B = 16KB each) is one CONTIGUOUS
// address range -> dense DRAM/L3 streaming (vs the old 512B-per-4KB gather
// that capped at ~3.3 TB/s). Stage is linear global_load_lds; LDS reads are
// conflict-free (each 16-lane group spans a contiguous 256B window).
// Lane = t*16+jj: t = token slot (4/tile), jj = d-slice (8 elems: 2 int4 at
// d=jj*4 and d=64+jj*4). Fixed-base softmax wgt=exp(s-8) (exact, cancels).
__global__ __launch_bounds__(512) void k_attn(
    const int* __restrict__ kqx, const float* __restrict__ kscale,
    const int* __restrict__ vqx, const float* __restrict__ vscale,
    const float* __restrict__ qkv, float* __restrict__ pv_c,
    float* __restrict__ l_c)
{
    const int c = blockIdx.x;
    const int tok0b = c * CHUNK;
    const int tid = threadIdx.x;
    const int w = tid >> 6;          // wave = kv-head (uniform/wave)
    const int l = tid & 63;
    const int t = l >> 4, jj = l & 15;

    __shared__ int   kbuf[2][TB * HKV_ * 128];   // 16 KB per buf
    __shared__ int   vbuf[2][TB * HKV_ * 128];   // 16 KB per buf
    __shared__ float scb[2][64];                 // [0..31]=ksc[t*8+kh], [32..63]=vsc

    float4 qfa[4], qfb[4];
    #pragma unroll
    for (int g = 0; g < 4; ++g) {
        qfa[g] = *(const float4*)&qkv[(w * 4 + g) * D_ + jj * 4];
        qfb[g] = *(const float4*)&qkv[(w * 4 + g) * D_ + 64 + jj * 4];
    }

    float ls[4] = {0.f, 0.f, 0.f, 0.f};
    float4 accA[4], accB[4];
    #pragma unroll
    for (int g = 0; g < 4; ++g) {
        accA[g] = make_float4(0.f, 0.f, 0.f, 0.f);
        accB[g] = make_float4(0.f, 0.f, 0.f, 0.f);
    }

    // stage one tile: 32 KB contiguous K + V; wave w covers 2x1KB segs each
    auto stage = [&](int buf, int tok0) {
        #pragma unroll
        for (int i = 0; i < 2; ++i) {
            const int seg = w * 2 + i;                    // 0..15, 1 KB each
            const size_t src = (size_t)tok0 * 1024 + seg * 256 + l * 4;  // ints, linear
            GLOAD_LDS16(kqx + src, (char*)&kbuf[buf][0] + seg * 1024);
            GLOAD_LDS16(vqx + src, (char*)&vbuf[buf][0] + seg * 1024);
        }
        if (w == 0) {   // wave-uniform; 32 K-scales + 32 V-scales (contiguous)
            const float* gs = (l < 32) ? (kscale + (size_t)tok0 * HKV_ + l)
                                       : (vscale + (size_t)tok0 * HKV_ + (l - 32));
            GLOAD_LDS4(gs, (char*)&scb[buf][0]);
        }
    };

    stage(0, tok0b);
    __syncthreads();   // vmcnt(0) drain + barrier

    for (int tile = 0; tile < NT; ++tile) {
        if (tile + 1 < NT) stage((tile + 1) & 1, tok0b + (tile + 1) * TB);

        const int buf = tile & 1;
        const int base = t * 1024 + w * 128;   // ints: token row + kh slice
        const int4 kA = *(const int4*)&kbuf[buf][base + jj * 4];
        const int4 kB = *(const int4*)&kbuf[buf][base + 64 + jj * 4];
        const int4 vA = *(const int4*)&vbuf[buf][base + jj * 4];
        const int4 vB = *(const int4*)&vbuf[buf][base + 64 + jj * 4];
        const float ksc = scb[buf][t * 8 + w] * SCALE_;
        const float vsc = scb[buf][32 + t * 8 + w];

        const float a0 = (float)kA.x, a1 = (float)kA.y, a2 = (float)kA.z, a3 = (float)kA.w;
        const float b0 = (float)kB.x, b1 = (float)kB.y, b2 = (float)kB.z, b3 = (float)kB.w;
        float dot[4];
        #pragma unroll
        for (int g = 0; g < 4; ++g)
            dot[g] = a0 * qfa[g].x + a1 * qfa[g].y + a2 * qfa[g].z + a3 * qfa[g].w +
                     b0 * qfb[g].x + b1 * qfb[g].y + b2 * qfb[g].z + b3 * qfb[g].w;
        #pragma unroll
        for (int msk = 1; msk < 16; msk <<= 1) {
            #pragma unroll
            for (int g = 0; g < 4; ++g) dot[g] += __shfl_xor(dot[g], msk, 64);
        }
        float wv[4];
        #pragma unroll
        for (int g = 0; g < 4; ++g) {
            const float wgt = __expf(dot[g] * ksc - BASE_);
            ls[g] += wgt;
            wv[g] = wgt * vsc;
        }
        const float c0f = (float)vA.x, c1f = (float)vA.y, c2f = (float)vA.z, c3f = (float)vA.w;
        const float d0f = (float)vB.x, d1f = (float)vB.y, d2f = (float)vB.z, d3f = (float)vB.w;
        #pragma unroll
        for (int g = 0; g < 4; ++g) {
            accA[g].x += wv[g] * c0f; accA[g].y += wv[g] * c1f;
            accA[g].z += wv[g] * c2f; accA[g].w += wv[g] * c3f;
            accB[g].x += wv[g] * d0f; accB[g].y += wv[g] * d1f;
            accB[g].z += wv[g] * d2f; accB[g].w += wv[g] * d3f;
        }
        __syncthreads();   // stage(tile+1) landed + all waves done reading buf
    }

    // reduce across the 4 token slots (lane bits 4,5); jj-lanes hold disjoint d
    #pragma unroll
    for (int msk = 16; msk < 64; msk <<= 1) {
        #pragma unroll
        for (int g = 0; g < 4; ++g) {
            accA[g].x += __shfl_xor(accA[g].x, msk, 64);
            accA[g].y += __shfl_xor(accA[g].y, msk, 64);
            accA[g].z += __shfl_xor(accA[g].z, msk, 64);
            accA[g].w += __shfl_xor(accA[g].w, msk, 64);
            accB[g].x += __shfl_xor(accB[g].x, msk, 64);
            accB[g].y += __shfl_xor(accB[g].y, msk, 64);
            accB[g].z += __shfl_xor(accB[g].z, msk, 64);
            accB[g].w += __shfl_xor(accB[g].w, msk, 64);
            ls[g] += __shfl_xor(ls[g], msk, 64);
        }
    }
    if (t == 0) {   // lanes 0..15 = jj
        #pragma unroll
        for (int g = 0; g < 4; ++g) {
            float* dst = pv_c + (((size_t)c * HKV_ + w) * 4 + g) * D_;
            *(float4*)(dst + jj * 4) = accA[g];
            *(float4*)(dst + 64 + jj * 4) = accB[g];
        }
        if (jj == 0) {
            #pragma unroll
            for (int g = 0; g < 4; ++g) l_c[((size_t)c * HKV_ + w) * 4 + g] = ls[g];
        }
    }
}

// ---------------- kernel 4: combine (pure sums, fixed base) ----------------
// one block per head; 128 threads = d
__global__ __launch_bounds__(128) void k_combine(
    const float* __restrict__ pv_c, const float* __restrict__ l_c,
    const float* __restrict__ qkv, float* __restrict__ attn)
{
    const int h = blockIdx.x;        // 32 blocks
    const int d = threadIdx.x;       // 128
    const int kh = h >> 2, g = h & 3;

    __shared__ float sred[128];
    sred[d] = qkv[h * D_ + d] * qkv[4096 + kh * D_ + d];
    __syncthreads();
    for (int s2 = 64; s2 > 0; s2 >>= 1) {
        if (d < s2) sred[d] += sred[d + s2];
        __syncthreads();
    }
    const float pc = __expf(sred[0] * SCALE_ - BASE_);  // current-token weight

    float pv = 0.f, dsum = 0.f;
    #pragma unroll 4
    for (int c = 0; c < NCHUNK; ++c) {
        pv   += pv_c[(((size_t)c * HKV_ + kh) * 4 + g) * D_ + d];
        dsum += l_c[((size_t)c * HKV_ + kh) * 4 + g];
    }
    const float vcur = qkv[5120 + kh * D_ + d];
    attn[h * D_ + d] = (pv + pc * vcur) / (dsum + pc);
}

// ---------------- kernel 5: output GEMV split-K partials ----------------
__global__ __launch_bounds__(256) void k_out_part(
    const float* __restrict__ attn, const float* __restrict__ Wo,
    float* __restrict__ opart)
{
    const int j0 = blockIdx.x * 1024 + threadIdx.x * 4;  // 4 col-blocks
    const int i0 = blockIdx.y * (HID_ / SPLIT);
    __shared__ float hs[HID_ / SPLIT];
    if (threadIdx.x < HID_ / SPLIT) hs[threadIdx.x] = attn[i0 + threadIdx.x];
    __syncthreads();
    float4 acc = {0.f, 0.f, 0.f, 0.f};
    const float* p = Wo + (size_t)i0 * HID_ + j0;
    #pragma unroll 8
    for (int i = 0; i < HID_ / SPLIT; ++i) {
        const float4 wv = *(const float4*)(p + (size_t)i * HID_);
        const float h = hs[i];
        acc.x += h * wv.x; acc.y += h * wv.y; acc.z += h * wv.z; acc.w += h * wv.w;
    }
    *(float4*)&opart[(size_t)blockIdx.y * HID_ + j0] = acc;
}

// ---------------- kernel 6: reduce output partials ----------------
__global__ __launch_bounds__(256) void k_out_reduce(
    const float* __restrict__ opart, float* __restrict__ out)
{
    const int j = blockIdx.x * 256 + threadIdx.x;  // 16 blocks
    float s = 0.f;
    #pragma unroll 8
    for (int k = 0; k < SPLIT; ++k) s += opart[(size_t)k * HID_ + j];
    out[j] = s;
}

extern "C" void kernel_launch(void* const* d_in, const int* in_sizes, int n_in,
                              void* d_out, int out_size, void* d_ws, size_t ws_size,
                              hipStream_t stream) {
    const float* hid    = (const float*)d_in[0];
    const int*   kqx    = (const int*)d_in[1];
    const float* kscale = (const float*)d_in[2];
    const int*   vqx    = (const int*)d_in[3];
    const float* vscale = (const float*)d_in[4];
    const float* cosv   = (const float*)d_in[5];
    const float* sinv   = (const float*)d_in[6];
    const float* Wq     = (const float*)d_in[7];
    const float* Wk     = (const float*)d_in[8];
    const float* Wv     = (const float*)d_in[9];
    const float* Wo     = (const float*)d_in[10];
    float* ws  = (float*)d_ws;
    float* out = (float*)d_out;

    k_qkv_part  <<<dim3(6, SPLIT), 256, 0, stream>>>(hid, Wq, Wk, Wv, ws + WS_QKV_PART);
    k_qkv_reduce<<<dim3(24),       256, 0, stream>>>(ws + WS_QKV_PART, cosv, sinv, ws + WS_QKV);
    k_attn      <<<dim3(NCHUNK),   512, 0, stream>>>(kqx, kscale, vqx, vscale,
                                                     ws + WS_QKV, ws + WS_PV_C,
                                                     ws + WS_L_C);
    k_combine   <<<dim3(H_),       128, 0, stream>>>(ws + WS_PV_C, ws + WS_L_C,
                                                     ws + WS_QKV, ws + WS_ATTN);
    k_out_part  <<<dim3(4, SPLIT), 256, 0, stream>>>(ws + WS_ATTN, Wo, ws + WS_OPART);
    k_out_reduce<<<dim3(16),       256, 0, stream>>>(ws + WS_OPART, out);
}